// Round 5
// baseline (466.403 us; speedup 1.0000x reference)
//
#include <hip/hip_runtime.h>
#include <hip/hip_bf16.h>

// Swin-V2 window attention, fused one-block-per-window, wave=head design.
// All I/O fp32. B=32, H=W=64, C=60, NH=6, hd=10, WS=7 -> pad 70, nw=10,
// 3200 windows x 49 tokens. Block = 384 threads = 6 waves; wave w owns head w:
//   qkv (q stays in registers, k/v normalized in-reg -> LDS row-major),
//   attention with wave-uniform j (k/v reads are same-address LDS broadcasts),
//   projection of channels 10w..10w+9. 2 barriers total.

#define WSZ 7
#define NT 49
#define CH 60
#define IMG 64
#define LOG100F 4.605170185988092f

__global__ __launch_bounds__(384, 4)
void swin_win_attn(const float* __restrict__ x,
                   const float* __restrict__ qkv_w,
                   const float* __restrict__ qkv_b,
                   const float* __restrict__ logit_scale,
                   const float* __restrict__ proj_w,
                   const float* __restrict__ proj_b,
                   float* __restrict__ out)
{
    __shared__ __align__(16) float s_k[6 * NT * 12];   // row-major, 48B rows
    __shared__ __align__(16) float s_v[6 * NT * 12];
    __shared__ __align__(16) float s_o[CH * NT];        // transposed [c][t]

    const int tid  = threadIdx.x;
    const int lane = tid & 63;
    const int wv   = __builtin_amdgcn_readfirstlane(tid >> 6);  // wave id = head id
    const int w  = blockIdx.x;
    const int b  = w / 100;
    const int wy = (w / 10) % 10;
    const int wx = w % 10;

    const int  t      = (lane < NT) ? lane : NT - 1;
    const bool vt     = (lane < NT);
    const int  r      = wy * WSZ + t / WSZ;
    const int  cc     = wx * WSZ + t % WSZ;
    const bool in_img = (r < IMG) && (cc < IMG);

    // ---- x row for this token straight into registers (15 x float4) ----
    float4 xr[15];
    if (vt && in_img) {
        const float4* xp = reinterpret_cast<const float4*>(x + ((b * IMG + r) * IMG + cc) * CH);
        #pragma unroll
        for (int m = 0; m < 15; ++m) xr[m] = xp[m];
    } else {
        #pragma unroll
        for (int m = 0; m < 15; ++m) xr[m] = make_float4(0.f, 0.f, 0.f, 0.f);
    }

    // ---- Phase 2: q,k,v rows for head wv (weights wave-uniform -> s_load) ----
    float q[10];
    {   // q: out rows wv*10 .. +9
        const float* wb = qkv_w + (wv * 10) * CH;
        #pragma unroll
        for (int u = 0; u < 10; ++u) q[u] = qkv_b[wv * 10 + u];
        for (int m = 0; m < 15; ++m) {
            float4 xv = xr[m];
            #pragma unroll
            for (int u = 0; u < 10; ++u) {
                float4 wv4 = *reinterpret_cast<const float4*>(wb + u * CH + 4 * m);
                q[u] += xv.x * wv4.x + xv.y * wv4.y + xv.z * wv4.z + xv.w * wv4.w;
            }
        }
        float ss = 0.f;
        #pragma unroll
        for (int u = 0; u < 10; ++u) ss += q[u] * q[u];
        float inv = 1.f / fmaxf(sqrtf(ss), 1e-12f);
        #pragma unroll
        for (int u = 0; u < 10; ++u) q[u] *= inv;
    }
    {   // k: out rows 60 + wv*10, normalized in-reg, then LDS
        const float* wb = qkv_w + (CH + wv * 10) * CH;
        float kk[10];
        #pragma unroll
        for (int u = 0; u < 10; ++u) kk[u] = qkv_b[CH + wv * 10 + u];
        for (int m = 0; m < 15; ++m) {
            float4 xv = xr[m];
            #pragma unroll
            for (int u = 0; u < 10; ++u) {
                float4 wv4 = *reinterpret_cast<const float4*>(wb + u * CH + 4 * m);
                kk[u] += xv.x * wv4.x + xv.y * wv4.y + xv.z * wv4.z + xv.w * wv4.w;
            }
        }
        float ss = 0.f;
        #pragma unroll
        for (int u = 0; u < 10; ++u) ss += kk[u] * kk[u];
        float inv = 1.f / fmaxf(sqrtf(ss), 1e-12f);
        if (vt) {
            float* kp = s_k + (wv * NT + t) * 12;
            #pragma unroll
            for (int u = 0; u < 10; ++u) kp[u] = kk[u] * inv;
            kp[10] = 0.f; kp[11] = 0.f;
        }
    }
    {   // v: out rows 120 + wv*10 -> LDS
        const float* wb = qkv_w + (2 * CH + wv * 10) * CH;
        float vv[10];
        #pragma unroll
        for (int u = 0; u < 10; ++u) vv[u] = qkv_b[2 * CH + wv * 10 + u];
        for (int m = 0; m < 15; ++m) {
            float4 xv = xr[m];
            #pragma unroll
            for (int u = 0; u < 10; ++u) {
                float4 wv4 = *reinterpret_cast<const float4*>(wb + u * CH + 4 * m);
                vv[u] += xv.x * wv4.x + xv.y * wv4.y + xv.z * wv4.z + xv.w * wv4.w;
            }
        }
        if (vt) {
            float* vp = s_v + (wv * NT + t) * 12;
            #pragma unroll
            for (int u = 0; u < 10; ++u) vp[u] = vv[u];
            vp[10] = 0.f; vp[11] = 0.f;
        }
    }
    __syncthreads();

    // ---- Phase 4: attention for head wv; lane = q-row; j wave-uniform ----
    {
        float scale = __expf(fminf(logit_scale[wv], LOG100F));  // uniform
        float a[NT];
        const float4* kb = reinterpret_cast<const float4*>(s_k) + (wv * NT) * 3;
        #pragma unroll
        for (int j = 0; j < NT; ++j) {            // same-address -> LDS broadcast
            float4 k0 = kb[j * 3 + 0];
            float4 k1 = kb[j * 3 + 1];
            float4 k2 = kb[j * 3 + 2];
            float dp = q[0]*k0.x + q[1]*k0.y + q[2]*k0.z + q[3]*k0.w
                     + q[4]*k1.x + q[5]*k1.y + q[6]*k1.z + q[7]*k1.w
                     + q[8]*k2.x + q[9]*k2.y;
            a[j] = dp * scale;
        }
        float m = a[0];
        #pragma unroll
        for (int j = 1; j < NT; ++j) m = fmaxf(m, a[j]);
        float s = 0.f;
        #pragma unroll
        for (int j = 0; j < NT; ++j) { float e = __expf(a[j] - m); a[j] = e; s += e; }
        float o[10];
        #pragma unroll
        for (int d = 0; d < 10; ++d) o[d] = 0.f;
        const float4* vb = reinterpret_cast<const float4*>(s_v) + (wv * NT) * 3;
        #pragma unroll
        for (int j = 0; j < NT; ++j) {            // broadcast again
            float4 v0 = vb[j * 3 + 0];
            float4 v1 = vb[j * 3 + 1];
            float4 v2 = vb[j * 3 + 2];
            float aj = a[j];
            o[0] += aj * v0.x; o[1] += aj * v0.y; o[2] += aj * v0.z; o[3] += aj * v0.w;
            o[4] += aj * v1.x; o[5] += aj * v1.y; o[6] += aj * v1.z; o[7] += aj * v1.w;
            o[8] += aj * v2.x; o[9] += aj * v2.y;
        }
        float inv = 1.f / s;
        if (vt) {
            #pragma unroll
            for (int d = 0; d < 10; ++d)          // consecutive-lane b32: conflict-free
                s_o[(wv * 10 + d) * NT + t] = o[d] * inv;
        }
    }
    __syncthreads();

    // ---- Phase 5: projection channels 10wv..10wv+9 (uniform weights) ----
    {
        float acc[10];
        #pragma unroll
        for (int u = 0; u < 10; ++u) acc[u] = proj_b[wv * 10 + u];
        const float* wb = proj_w + (wv * 10) * CH;
        for (int m = 0; m < 15; ++m) {
            float xc0 = s_o[(4 * m + 0) * NT + t];   // conflict-free b32
            float xc1 = s_o[(4 * m + 1) * NT + t];
            float xc2 = s_o[(4 * m + 2) * NT + t];
            float xc3 = s_o[(4 * m + 3) * NT + t];
            #pragma unroll
            for (int u = 0; u < 10; ++u) {
                float4 wv4 = *reinterpret_cast<const float4*>(wb + u * CH + 4 * m);
                acc[u] += xc0 * wv4.x + xc1 * wv4.y + xc2 * wv4.z + xc3 * wv4.w;
            }
        }
        if (vt && in_img) {
            float* op = out + ((b * IMG + r) * IMG + cc) * CH + wv * 10;
            #pragma unroll
            for (int u = 0; u < 5; ++u)
                *reinterpret_cast<float2*>(op + 2 * u) =
                    make_float2(acc[2 * u], acc[2 * u + 1]);
        }
    }
}

extern "C" void kernel_launch(void* const* d_in, const int* in_sizes, int n_in,
                              void* d_out, int out_size, void* d_ws, size_t ws_size,
                              hipStream_t stream) {
    hipLaunchKernelGGL(swin_win_attn, dim3(3200), dim3(384), 0, stream,
                       (const float*)d_in[0], (const float*)d_in[1],
                       (const float*)d_in[2], (const float*)d_in[3],
                       (const float*)d_in[4], (const float*)d_in[5],
                       (float*)d_out);
}

// Round 6
// 445.360 us; speedup vs baseline: 1.0472x; 1.0472x over previous
//
#include <hip/hip_runtime.h>
#include <hip/hip_bf16.h>

// Swin-V2 window attention, fused one-block-per-window, wave=head design.
// All I/O fp32. B=32, H=W=64, C=60, NH=6, hd=10, WS=7 -> pad 70, nw=10,
// 3200 windows x 49 tokens. Block = 384 threads = 6 waves; wave w owns head w.
//
// R5 post-mortem: __launch_bounds__(384,4) capped VGPR at 64 -> ~525 MB of
// scratch spill traffic (WRITE_SIZE 350 MB) = the whole 466 us runtime.
// R6: (384,2) -> 256-VGPR cap; live state ~110-130 VGPRs, no spills,
// 2 blocks/CU (VGPR-bound; LDS 40.4 KB would allow 3).

#define WSZ 7
#define NT 49
#define CH 60
#define IMG 64
#define LOG100F 4.605170185988092f

__global__ __launch_bounds__(384, 2)
void swin_win_attn(const float* __restrict__ x,
                   const float* __restrict__ qkv_w,
                   const float* __restrict__ qkv_b,
                   const float* __restrict__ logit_scale,
                   const float* __restrict__ proj_w,
                   const float* __restrict__ proj_b,
                   float* __restrict__ out)
{
    __shared__ __align__(16) float s_k[6 * NT * 12];   // row-major, 48B rows
    __shared__ __align__(16) float s_v[6 * NT * 12];
    __shared__ __align__(16) float s_o[CH * NT];        // transposed [c][t]

    const int tid  = threadIdx.x;
    const int lane = tid & 63;
    const int wv   = __builtin_amdgcn_readfirstlane(tid >> 6);  // wave id = head id
    const int w  = blockIdx.x;
    const int b  = w / 100;
    const int wy = (w / 10) % 10;
    const int wx = w % 10;

    const int  t      = (lane < NT) ? lane : NT - 1;
    const bool vt     = (lane < NT);
    const int  r      = wy * WSZ + t / WSZ;
    const int  cc     = wx * WSZ + t % WSZ;
    const bool in_img = (r < IMG) && (cc < IMG);

    // ---- x row for this token straight into registers (15 x float4) ----
    float4 xr[15];
    if (vt && in_img) {
        const float4* xp = reinterpret_cast<const float4*>(x + ((b * IMG + r) * IMG + cc) * CH);
        #pragma unroll
        for (int m = 0; m < 15; ++m) xr[m] = xp[m];
    } else {
        #pragma unroll
        for (int m = 0; m < 15; ++m) xr[m] = make_float4(0.f, 0.f, 0.f, 0.f);
    }

    // ---- Phase 2: q,k,v rows for head wv (weights wave-uniform -> s_load) ----
    float q[10];
    {   // q: out rows wv*10 .. +9
        const float* wb = qkv_w + (wv * 10) * CH;
        #pragma unroll
        for (int u = 0; u < 10; ++u) q[u] = qkv_b[wv * 10 + u];
        for (int m = 0; m < 15; ++m) {
            float4 xv = xr[m];
            #pragma unroll
            for (int u = 0; u < 10; ++u) {
                float4 wv4 = *reinterpret_cast<const float4*>(wb + u * CH + 4 * m);
                q[u] += xv.x * wv4.x + xv.y * wv4.y + xv.z * wv4.z + xv.w * wv4.w;
            }
        }
        float ss = 0.f;
        #pragma unroll
        for (int u = 0; u < 10; ++u) ss += q[u] * q[u];
        float inv = 1.f / fmaxf(sqrtf(ss), 1e-12f);
        #pragma unroll
        for (int u = 0; u < 10; ++u) q[u] *= inv;
    }
    {   // k: out rows 60 + wv*10, normalized in-reg, then LDS
        const float* wb = qkv_w + (CH + wv * 10) * CH;
        float kk[10];
        #pragma unroll
        for (int u = 0; u < 10; ++u) kk[u] = qkv_b[CH + wv * 10 + u];
        for (int m = 0; m < 15; ++m) {
            float4 xv = xr[m];
            #pragma unroll
            for (int u = 0; u < 10; ++u) {
                float4 wv4 = *reinterpret_cast<const float4*>(wb + u * CH + 4 * m);
                kk[u] += xv.x * wv4.x + xv.y * wv4.y + xv.z * wv4.z + xv.w * wv4.w;
            }
        }
        float ss = 0.f;
        #pragma unroll
        for (int u = 0; u < 10; ++u) ss += kk[u] * kk[u];
        float inv = 1.f / fmaxf(sqrtf(ss), 1e-12f);
        if (vt) {
            float* kp = s_k + (wv * NT + t) * 12;
            #pragma unroll
            for (int u = 0; u < 10; ++u) kp[u] = kk[u] * inv;
            kp[10] = 0.f; kp[11] = 0.f;
        }
    }
    {   // v: out rows 120 + wv*10 -> LDS
        const float* wb = qkv_w + (2 * CH + wv * 10) * CH;
        float vv[10];
        #pragma unroll
        for (int u = 0; u < 10; ++u) vv[u] = qkv_b[2 * CH + wv * 10 + u];
        for (int m = 0; m < 15; ++m) {
            float4 xv = xr[m];
            #pragma unroll
            for (int u = 0; u < 10; ++u) {
                float4 wv4 = *reinterpret_cast<const float4*>(wb + u * CH + 4 * m);
                vv[u] += xv.x * wv4.x + xv.y * wv4.y + xv.z * wv4.z + xv.w * wv4.w;
            }
        }
        if (vt) {
            float* vp = s_v + (wv * NT + t) * 12;
            #pragma unroll
            for (int u = 0; u < 10; ++u) vp[u] = vv[u];
            vp[10] = 0.f; vp[11] = 0.f;
        }
    }
    __syncthreads();

    // ---- Phase 4: attention for head wv; lane = q-row; j wave-uniform ----
    {
        float scale = __expf(fminf(logit_scale[wv], LOG100F));  // uniform
        float a[NT];
        const float4* kb = reinterpret_cast<const float4*>(s_k) + (wv * NT) * 3;
        #pragma unroll
        for (int j = 0; j < NT; ++j) {            // same-address -> LDS broadcast
            float4 k0 = kb[j * 3 + 0];
            float4 k1 = kb[j * 3 + 1];
            float4 k2 = kb[j * 3 + 2];
            float dp = q[0]*k0.x + q[1]*k0.y + q[2]*k0.z + q[3]*k0.w
                     + q[4]*k1.x + q[5]*k1.y + q[6]*k1.z + q[7]*k1.w
                     + q[8]*k2.x + q[9]*k2.y;
            a[j] = dp * scale;
        }
        float m = a[0];
        #pragma unroll
        for (int j = 1; j < NT; ++j) m = fmaxf(m, a[j]);
        float s = 0.f;
        #pragma unroll
        for (int j = 0; j < NT; ++j) { float e = __expf(a[j] - m); a[j] = e; s += e; }
        float o[10];
        #pragma unroll
        for (int d = 0; d < 10; ++d) o[d] = 0.f;
        const float4* vb = reinterpret_cast<const float4*>(s_v) + (wv * NT) * 3;
        #pragma unroll
        for (int j = 0; j < NT; ++j) {            // broadcast again
            float4 v0 = vb[j * 3 + 0];
            float4 v1 = vb[j * 3 + 1];
            float4 v2 = vb[j * 3 + 2];
            float aj = a[j];
            o[0] += aj * v0.x; o[1] += aj * v0.y; o[2] += aj * v0.z; o[3] += aj * v0.w;
            o[4] += aj * v1.x; o[5] += aj * v1.y; o[6] += aj * v1.z; o[7] += aj * v1.w;
            o[8] += aj * v2.x; o[9] += aj * v2.y;
        }
        float inv = 1.f / s;
        if (vt) {
            #pragma unroll
            for (int d = 0; d < 10; ++d)          // consecutive-lane b32: conflict-free
                s_o[(wv * 10 + d) * NT + t] = o[d] * inv;
        }
    }
    __syncthreads();

    // ---- Phase 5: projection channels 10wv..10wv+9 (uniform weights) ----
    {
        float acc[10];
        #pragma unroll
        for (int u = 0; u < 10; ++u) acc[u] = proj_b[wv * 10 + u];
        const float* wb = proj_w + (wv * 10) * CH;
        for (int m = 0; m < 15; ++m) {
            float xc0 = s_o[(4 * m + 0) * NT + t];   // conflict-free b32
            float xc1 = s_o[(4 * m + 1) * NT + t];
            float xc2 = s_o[(4 * m + 2) * NT + t];
            float xc3 = s_o[(4 * m + 3) * NT + t];
            #pragma unroll
            for (int u = 0; u < 10; ++u) {
                float4 wv4 = *reinterpret_cast<const float4*>(wb + u * CH + 4 * m);
                acc[u] += xc0 * wv4.x + xc1 * wv4.y + xc2 * wv4.z + xc3 * wv4.w;
            }
        }
        if (vt && in_img) {
            float* op = out + ((b * IMG + r) * IMG + cc) * CH + wv * 10;
            #pragma unroll
            for (int u = 0; u < 5; ++u)
                *reinterpret_cast<float2*>(op + 2 * u) =
                    make_float2(acc[2 * u], acc[2 * u + 1]);
        }
    }
}

extern "C" void kernel_launch(void* const* d_in, const int* in_sizes, int n_in,
                              void* d_out, int out_size, void* d_ws, size_t ws_size,
                              hipStream_t stream) {
    hipLaunchKernelGGL(swin_win_attn, dim3(3200), dim3(384), 0, stream,
                       (const float*)d_in[0], (const float*)d_in[1],
                       (const float*)d_in[2], (const float*)d_in[3],
                       (const float*)d_in[4], (const float*)d_in[5],
                       (float*)d_out);
}

// Round 7
// 351.891 us; speedup vs baseline: 1.3254x; 1.2656x over previous
//
#include <hip/hip_runtime.h>
#include <hip/hip_bf16.h>

// Swin-V2 window attention, fused one-block-per-window. All I/O fp32.
// B=32, H=W=64, C=60, NH=6, hd=10, WS=7 -> pad 70, nw=10, 3200 windows x 49 tok.
//
// R7: channel-lane qkv/proj. Theory: R4/R6 were stalled on s_load weight
// streams thrashing the scalar K$ (43+14 KB per block through a ~16 KB K$,
// ~200cyc L2 wait per 40-FMA chunk). Now weight rows live in per-lane VGPRs
// (loaded once per block with 15-wide ILP), x comes from LDS same-address
// broadcasts (conflict-free). Phases 3/4 keep the R4 form.

#define WSZ 7
#define NT 49
#define CH 60
#define IMG 64
#define LOG100F 4.605170185988092f

__global__ __launch_bounds__(256, 3)
void swin_win_attn(const float* __restrict__ x,
                   const float* __restrict__ qkv_w,
                   const float* __restrict__ qkv_b,
                   const float* __restrict__ logit_scale,
                   const float* __restrict__ proj_w,
                   const float* __restrict__ proj_b,
                   float* __restrict__ out)
{
    __shared__ __align__(16) float s_x[NT * CH];     // [t][c] stride 60; aliased as s_out
    __shared__ __align__(16) float s_q[6 * NT * 10]; // [(h*49+t)*10+d]
    __shared__ __align__(16) float s_k[6 * NT * 10];
    __shared__ __align__(16) float s_v[6 * NT * 10]; // total 47,040 B -> 3 blocks/CU

    const int tid  = threadIdx.x;
    const int lane = tid & 63;
    const int wv   = __builtin_amdgcn_readfirstlane(tid >> 6);
    const int w  = blockIdx.x;
    const int b  = w / 100;
    const int wy = (w / 10) % 10;
    const int wx = w % 10;
    const int row0 = wy * WSZ;
    const int col0 = wx * WSZ;

    // ---- Phase 1: stage x tile (49x60, stride 60; rows 240B = 16B-aligned) ----
    for (int idx = tid; idx < NT * 15; idx += 256) {
        int t = idx / 15, m = idx - t * 15;
        int r  = row0 + t / WSZ;
        int cc = col0 + t % WSZ;
        float4 v = make_float4(0.f, 0.f, 0.f, 0.f);
        if (r < IMG && cc < IMG)
            v = reinterpret_cast<const float4*>(x + ((b * IMG + r) * IMG + cc) * CH)[m];
        *reinterpret_cast<float4*>(s_x + t * CH + 4 * m) = v;
    }
    __syncthreads();

    // ---- Phase 2: qkv. wave wv<3 = part (q/k/v); lane<60 = channel h*10+d.
    //      Weight row in 60 VGPRs; x via same-address LDS broadcast b128. ----
    if (wv < 3 && lane < 60) {
        float4 w4[15];
        const float4* wp = reinterpret_cast<const float4*>(qkv_w + (wv * 60 + lane) * CH);
        #pragma unroll
        for (int m = 0; m < 15; ++m) w4[m] = wp[m];   // 15 independent dwordx4
        const float bias = qkv_b[wv * 60 + lane];
        float* dst = (wv == 0) ? s_q : (wv == 1) ? s_k : s_v;
        const int h = lane / 10, d = lane - 10 * (lane / 10);
        for (int g = 0; g < 7; ++g) {                 // token groups of 7
            const float* xg = s_x + (7 * g) * CH;
            float acc[7];
            #pragma unroll
            for (int t7 = 0; t7 < 7; ++t7) {
                float a = bias;
                const float4* xr = reinterpret_cast<const float4*>(xg + t7 * CH);
                #pragma unroll
                for (int m = 0; m < 15; ++m) {
                    float4 xv = xr[m];                // broadcast: same addr all lanes
                    a += xv.x * w4[m].x + xv.y * w4[m].y
                       + xv.z * w4[m].z + xv.w * w4[m].w;
                }
                acc[t7] = a;
            }
            float* dg = dst + h * 490 + (7 * g) * 10 + d;
            #pragma unroll
            for (int t7 = 0; t7 < 7; ++t7) dg[t7 * 10] = acc[t7];
        }
    }
    __syncthreads();

    // ---- Phase 3: L2-normalize q,k rows (clamp 1e-12); stride 10 -> 2-way free ----
    for (int item = tid; item < 2 * 6 * NT; item += 256) {
        int which = item / (6 * NT);
        int r = item - which * (6 * NT);
        float* p = (which == 0) ? (s_q + r * 10) : (s_k + r * 10);
        float ss = 0.f;
        #pragma unroll
        for (int d = 0; d < 10; ++d) ss += p[d] * p[d];
        float inv = 1.f / fmaxf(sqrtf(ss), 1e-12f);
        #pragma unroll
        for (int d = 0; d < 10; ++d) p[d] *= inv;
    }
    __syncthreads();

    // ---- Phase 4: attention, one (head,row) per thread (294 items) ----
    for (int r = tid; r < 6 * NT; r += 256) {
        int h = r / NT, i = r - h * NT;
        float scale = __expf(fminf(logit_scale[h], LOG100F));
        float q[10];
        {
            const float2* qp = reinterpret_cast<const float2*>(s_q + r * 10);
            #pragma unroll
            for (int d = 0; d < 5; ++d) { float2 t2 = qp[d]; q[2*d] = t2.x; q[2*d+1] = t2.y; }
        }
        float a[NT];
        const float2* kb = reinterpret_cast<const float2*>(s_k + h * 490);
        #pragma unroll
        for (int j = 0; j < NT; ++j) {
            const float2* kp = kb + j * 5;
            float2 k0 = kp[0], k1 = kp[1], k2 = kp[2], k3 = kp[3], k4 = kp[4];
            float dp = q[0]*k0.x + q[1]*k0.y + q[2]*k1.x + q[3]*k1.y
                     + q[4]*k2.x + q[5]*k2.y + q[6]*k3.x + q[7]*k3.y
                     + q[8]*k4.x + q[9]*k4.y;
            a[j] = dp * scale;
        }
        float m = a[0];
        #pragma unroll
        for (int j = 1; j < NT; ++j) m = fmaxf(m, a[j]);
        float s = 0.f;
        #pragma unroll
        for (int j = 0; j < NT; ++j) { float e = __expf(a[j] - m); a[j] = e; s += e; }
        float o[10];
        #pragma unroll
        for (int d = 0; d < 10; ++d) o[d] = 0.f;
        const float2* vb = reinterpret_cast<const float2*>(s_v + h * 490);
        #pragma unroll
        for (int j = 0; j < NT; ++j) {
            const float2* vp = vb + j * 5;
            float2 v0 = vp[0], v1 = vp[1], v2 = vp[2], v3 = vp[3], v4 = vp[4];
            float aj = a[j];
            o[0] += aj * v0.x; o[1] += aj * v0.y; o[2] += aj * v1.x; o[3] += aj * v1.y;
            o[4] += aj * v2.x; o[5] += aj * v2.y; o[6] += aj * v3.x; o[7] += aj * v3.y;
            o[8] += aj * v4.x; o[9] += aj * v4.y;
        }
        float inv = 1.f / s;
        float* op = s_x + i * CH + h * 10;   // s_out aliases s_x (dead after P2)
        #pragma unroll
        for (int d = 0; d < 10; ++d) op[d] = o[d] * inv;
    }
    __syncthreads();

    // ---- Phase 5: proj. lane<60 = out channel, W-row in regs, tokens strided
    //      across the 4 waves; coalesced 240B global stores per token. ----
    if (lane < 60) {
        float4 w4[15];
        const float4* wp = reinterpret_cast<const float4*>(proj_w + lane * CH);
        #pragma unroll
        for (int m = 0; m < 15; ++m) w4[m] = wp[m];
        const float bias = proj_b[lane];
        for (int t = wv; t < NT; t += 4) {
            int r  = row0 + t / WSZ;
            int cc = col0 + t % WSZ;
            float a = bias;
            const float4* xr = reinterpret_cast<const float4*>(s_x + t * CH);
            #pragma unroll
            for (int m = 0; m < 15; ++m) {
                float4 xv = xr[m];                    // broadcast
                a += xv.x * w4[m].x + xv.y * w4[m].y
                   + xv.z * w4[m].z + xv.w * w4[m].w;
            }
            if (r < IMG && cc < IMG)
                out[((b * IMG + r) * IMG + cc) * CH + lane] = a;   // coalesced
        }
    }
}

extern "C" void kernel_launch(void* const* d_in, const int* in_sizes, int n_in,
                              void* d_out, int out_size, void* d_ws, size_t ws_size,
                              hipStream_t stream) {
    hipLaunchKernelGGL(swin_win_attn, dim3(3200), dim3(256), 0, stream,
                       (const float*)d_in[0], (const float*)d_in[1],
                       (const float*)d_in[2], (const float*)d_in[3],
                       (const float*)d_in[4], (const float*)d_in[5],
                       (float*)d_out);
}